// Round 10
// baseline (517.273 us; speedup 1.0000x reference)
//
#include <hip/hip_runtime.h>

#define N_NODES 100000
#define NEDGE   1600000
#define NHID    128
#define NCLASS  40

#define AGG_NODES 128
#define COLV_LDS  3072
#define FILL_SLICES 8
#define FILL_RANGE  12500   // N_NODES / FILL_SLICES
#define WPREP_TOT   264192  // 6*16384 + 147456 + 18432

using bf16x8 = __attribute__((ext_vector_type(8))) short;
using f32x4  = __attribute__((ext_vector_type(4))) float;

__device__ __forceinline__ float bf2f(unsigned short s) {
    unsigned u = ((unsigned)s) << 16; float f; __builtin_memcpy(&f, &u, 4); return f;
}
__device__ __forceinline__ unsigned short f2bf(float f) {
    unsigned u; __builtin_memcpy(&u, &f, 4);
    u = u + 0x7fffu + ((u >> 16) & 1u);          // RNE
    return (unsigned short)(u >> 16);
}

// global -> LDS direct (16B/lane). Dest: wave-uniform base; HW adds lane*16.
__device__ __forceinline__ void gld16(const void* g, void* l) {
    __builtin_amdgcn_global_load_lds(g, l, 16, 0, 0);
}

// ---------------- CSR build ----------------
__global__ __launch_bounds__(256) void k_countr(const int* __restrict__ ei, int* __restrict__ cnt) {
    int slice = blockIdx.x & 7;
    int e = (blockIdx.x >> 3) * 256 + threadIdx.x;
    if (e >= NEDGE) return;
    int d = ei[NEDGE + e];
    int lo = slice * FILL_RANGE;
    if (d >= lo && d < lo + FILL_RANGE) atomicAdd(&cnt[d], 1);
}

__global__ void k_scan1(const int* __restrict__ cnt, int* __restrict__ rp, int* __restrict__ bsum) {
    __shared__ int sh[256];
    int t = threadIdx.x, base = blockIdx.x * 1024;
    int v[4]; int s = 0;
    for (int k = 0; k < 4; ++k) { int i = base + t * 4 + k; v[k] = (i < N_NODES) ? cnt[i] : 0; s += v[k]; }
    sh[t] = s; __syncthreads();
    for (int off = 1; off < 256; off <<= 1) {
        int x = (t >= off) ? sh[t - off] : 0;
        __syncthreads();
        sh[t] += x;
        __syncthreads();
    }
    int excl = sh[t] - s;
    for (int k = 0; k < 4; ++k) { int i = base + t * 4 + k; if (i < N_NODES) rp[i] = excl; excl += v[k]; }
    if (t == 255) bsum[blockIdx.x] = sh[255];
}

__global__ void k_scan2(int* __restrict__ bsum, int nb) {
    __shared__ int sh[256];
    int t = threadIdx.x;
    int v = (t < nb) ? bsum[t] : 0;
    sh[t] = v; __syncthreads();
    for (int off = 1; off < 256; off <<= 1) {
        int x = (t >= off) ? sh[t - off] : 0;
        __syncthreads();
        sh[t] += x;
        __syncthreads();
    }
    if (t < nb) bsum[t] = sh[t] - v;   // exclusive block offsets
}

__global__ void k_scan3(int* __restrict__ rp, const int* __restrict__ bsum, int* __restrict__ cur) {
    int base = blockIdx.x * 1024;
    int off = bsum[blockIdx.x];
    for (int k = 0; k < 4; ++k) {
        int i = base + threadIdx.x * 4 + k;
        if (i < N_NODES) { int v = rp[i] + off; rp[i] = v; cur[i] = v; }
    }
    if (blockIdx.x == 0 && threadIdx.x == 0) rp[N_NODES] = NEDGE;
}

__global__ __launch_bounds__(256) void k_fillr(const int* __restrict__ ei,
                                               int* __restrict__ cur, int* __restrict__ colv) {
    int slice = blockIdx.x & 7;
    int e = (blockIdx.x >> 3) * 256 + threadIdx.x;
    if (e >= NEDGE) return;
    int d = ei[NEDGE + e];
    int lo = slice * FILL_RANGE;
    if (d >= lo && d < lo + FILL_RANGE) {
        int p = atomicAdd(&cur[d], 1);
        colv[p] = ei[e];
    }
}

// ---------------- weight prep: ALL weights in one dispatch, fragment-major bf16 ----------------
__global__ void k_wprep_all(const float* __restrict__ g0, const float* __restrict__ g1,
                            const float* __restrict__ g2, const float* __restrict__ g3,
                            const float* __restrict__ g4, const float* __restrict__ g5,
                            const float* __restrict__ l1w, const float* __restrict__ l2w,
                            unsigned short* __restrict__ dst) {
    int idx = blockIdx.x * 256 + threadIdx.x;
    if (idx >= WPREP_TOT) return;
    const float* w; int local, K, O;
    if (idx < 98304) {
        int r = idx >> 14; local = idx & 16383; K = 128; O = 128;
        w = r == 0 ? g0 : r == 1 ? g1 : r == 2 ? g2 : r == 3 ? g3 : r == 4 ? g4 : g5;
    } else if (idx < 245760) {
        local = idx - 98304; K = 384; O = 384; w = l1w;
    } else {
        local = idx - 245760; K = 384; O = 40; w = l2w;
    }
    int kss = K >> 5;
    int e = local & 7, lane = (local >> 3) & 63, rest = local >> 9;
    int ks = rest % kss, ot = rest / kss;
    int c = ot * 16 + (lane & 15);
    int k = ks * 32 + (lane >> 4) * 8 + e;
    float v = (c < O) ? w[k * O + c] : 0.f;
    dst[idx] = f2bf(v);
}

// ---------------- x -> sliced bf16 layout [8][N][16] ----------------
__global__ void k_xprep(const float* __restrict__ x, unsigned short* __restrict__ xs) {
    int s = blockIdx.x & 7;
    int rest = (blockIdx.x >> 3) * 256 + threadIdx.x;
    if (rest >= N_NODES * 8) return;
    int n = rest >> 3, wrd = rest & 7;
    float2 v = *(const float2*)(x + (size_t)n * 128 + s * 16 + wrd * 2);
    ((unsigned*)xs)[(size_t)s * N_NODES * 8 + rest] =
        (unsigned)f2bf(v.x) | ((unsigned)f2bf(v.y) << 16);
}

// ---------------- aggregation, sliced + LDS colv + 8-deep gather MLP ----------------
__device__ __forceinline__ void acc8(float* acc, uint4 f, float m) {
    unsigned u[4] = {f.x, f.y, f.z, f.w};
    for (int d = 0; d < 4; ++d) {
        acc[2 * d]     = fmaf(m, bf2f((unsigned short)u[d]), acc[2 * d]);
        acc[2 * d + 1] = fmaf(m, bf2f((unsigned short)(u[d] >> 16)), acc[2 * d + 1]);
    }
}

__global__ __launch_bounds__(256) void k_aggs(const unsigned short* __restrict__ feat,
                                              unsigned short* __restrict__ tout,
                                              const int* __restrict__ rp,
                                              const int* __restrict__ colv) {
    __shared__ int scol[COLV_LDS + 8];
    __shared__ int srp[AGG_NODES + 1];
    const int s = blockIdx.x & 7;
    const int chunk = blockIdx.x >> 3;
    const int tid = threadIdx.x;
    const int nbase = chunk * AGG_NODES;

    for (int i = tid; i <= AGG_NODES; i += 256) {
        int n = nbase + i;
        srp[i] = rp[n <= N_NODES ? n : N_NODES];
    }
    __syncthreads();
    const int ebase = srp[0];
    const int ecount = srp[AGG_NODES] - ebase;
    const int elds = ecount < COLV_LDS ? ecount : COLV_LDS;
    for (int i = tid; i < elds; i += 256) scol[i] = colv[ebase + i];
    if (tid < 8) scol[elds + tid] = 0;
    __syncthreads();

    const unsigned* fs = (const unsigned*)feat + (size_t)s * N_NODES * 8;
    unsigned* ts = (unsigned*)tout + (size_t)s * N_NODES * 8;

    const int sub = tid >> 1, half = tid & 1;
    const int node = nbase + sub;
    if (node >= N_NODES) return;
    const int off = half * 4;
    const int e0 = srp[sub] - ebase, e1 = srp[sub + 1] - ebase;

    float acc[8];
    {
        uint4 a = *(const uint4*)(fs + (size_t)node * 8 + off);
        unsigned u[4] = {a.x, a.y, a.z, a.w};
        for (int d = 0; d < 4; ++d) {
            acc[2 * d]     = bf2f((unsigned short)u[d]);
            acc[2 * d + 1] = bf2f((unsigned short)(u[d] >> 16));
        }
    }

    if (ecount <= COLV_LDS) {
        int e = e0;
        const int efull = e0 + ((e1 - e0) & ~7);
        for (; e < efull; e += 8) {
            int j[8];
            #pragma unroll
            for (int k = 0; k < 8; ++k) j[k] = scol[e + k];
            uint4 f[8];
            #pragma unroll
            for (int k = 0; k < 8; ++k)
                f[k] = *(const uint4*)(fs + (size_t)j[k] * 8 + off);
            #pragma unroll
            for (int k = 0; k < 8; ++k) acc8(acc, f[k], 1.f);
        }
        if (e < e1) {
            int j[8]; float m[8];
            #pragma unroll
            for (int k = 0; k < 8; ++k) {
                int ee = e + k;
                bool v = ee < e1;
                j[k] = v ? scol[ee] : node;
                m[k] = v ? 1.f : 0.f;
            }
            uint4 f[8];
            #pragma unroll
            for (int k = 0; k < 8; ++k)
                f[k] = *(const uint4*)(fs + (size_t)j[k] * 8 + off);
            #pragma unroll
            for (int k = 0; k < 8; ++k) acc8(acc, f[k], m[k]);
        }
    } else {
        for (int e = e0; e < e1; e += 8) {
            int j[8]; float m[8];
            #pragma unroll
            for (int k = 0; k < 8; ++k) {
                int ee = e + k;
                bool v = ee < e1;
                int idx = ee < COLV_LDS ? scol[ee] : colv[ebase + ee];
                j[k] = v ? idx : node;
                m[k] = v ? 1.f : 0.f;
            }
            uint4 f[8];
            #pragma unroll
            for (int k = 0; k < 8; ++k)
                f[k] = *(const uint4*)(fs + (size_t)j[k] * 8 + off);
            #pragma unroll
            for (int k = 0; k < 8; ++k) acc8(acc, f[k], m[k]);
        }
    }

    uint4 o;
    o.x = (unsigned)f2bf(acc[0]) | ((unsigned)f2bf(acc[1]) << 16);
    o.y = (unsigned)f2bf(acc[2]) | ((unsigned)f2bf(acc[3]) << 16);
    o.z = (unsigned)f2bf(acc[4]) | ((unsigned)f2bf(acc[5]) << 16);
    o.w = (unsigned)f2bf(acc[6]) | ((unsigned)f2bf(acc[7]) << 16);
    *(uint4*)(ts + (size_t)node * 8 + off) = o;
}

// ---------------- fused GIN MLP, M=128, slice-major LDS sub-tiles ----------------
// LDS: tlds/hlds = 8 sub-tiles [slice][128 rows][32B] (4KB each, 32KB total).
// Staging: chunk = 32 consecutive nodes of ONE slice -> 1KB fully-contiguous wave-load.
// A-fragment (8 cols = 16B) lives inside one slice: addr = s*4096 + row*32 + (lg&1)*16.
__global__ __launch_bounds__(512) void k_mlp(
    const unsigned short* __restrict__ tin,
    const unsigned short* __restrict__ w1t, const float* __restrict__ b1,
    const unsigned short* __restrict__ w2t, const float* __restrict__ b2,
    unsigned short* __restrict__ hout) {
    __shared__ __align__(16) char tlds[8 * 4096];
    __shared__ __align__(16) char hlds[8 * 4096];
    const int tid = threadIdx.x, lane = tid & 63, w = tid >> 6;
    const int l15 = lane & 15, lg = lane >> 4;
    const int nbase = blockIdx.x * 128;

    // stage t tile: 32 chunks of 1KB, each = rows [rblk*32, +32) of slice s, contiguous
    #pragma unroll
    for (int i = 0; i < 4; ++i) {
        int c = w + i * 8;                 // chunk id [0,32)
        int s = c >> 2, rblk = c & 3;
        int node = nbase + rblk * 32 + (lane >> 1);
        if (node >= N_NODES) node = 0;
        gld16(tin + ((size_t)s * N_NODES + node) * 16 + (lane & 1) * 8,
              tlds + c * 1024);
    }

    // preload B1 AND B2 (wave w owns ot = w); B2 latency hides behind GEMM1
    bf16x8 B1[4], B2[4];
    const int col = w * 16 + l15;
    const float bias1 = b1[col], bias2 = b2[col];
    #pragma unroll
    for (int ks = 0; ks < 4; ++ks) {
        B1[ks] = *(const bf16x8*)(w1t + ((size_t)(w * 4 + ks) * 64 + lane) * 8);
        B2[ks] = *(const bf16x8*)(w2t + ((size_t)(w * 4 + ks) * 64 + lane) * 8);
    }
    __syncthreads();   // vmcnt(0) drains staging

    // GEMM1 -> relu -> hlds (A double-buffered over 8 m-tiles)
    {
        bf16x8 A[2][4];
        #pragma unroll
        for (int ks = 0; ks < 4; ++ks)
            A[0][ks] = *(const bf16x8*)(tlds + (2 * ks + (lg >> 1)) * 4096 + l15 * 32 + (lg & 1) * 16);
        #pragma unroll
        for (int m = 0; m < 8; ++m) {
            int cur = m & 1, nxt = cur ^ 1;
            if (m < 7) {
                int row = (m + 1) * 16 + l15;
                #pragma unroll
                for (int ks = 0; ks < 4; ++ks)
                    A[nxt][ks] = *(const bf16x8*)(tlds + (2 * ks + (lg >> 1)) * 4096 + row * 32 + (lg & 1) * 16);
            }
            f32x4 acc = {0.f, 0.f, 0.f, 0.f};
            #pragma unroll
            for (int ks = 0; ks < 4; ++ks)
                acc = __builtin_amdgcn_mfma_f32_16x16x32_bf16(A[cur][ks], B1[ks], acc, 0, 0, 0);
            #pragma unroll
            for (int r = 0; r < 4; ++r) {
                int row = m * 16 + lg * 4 + r;
                float v = acc[r] + bias1; v = v > 0.f ? v : 0.f;
                *(unsigned short*)(hlds + w * 4096 + row * 32 + l15 * 2) = f2bf(v);
            }
        }
    }
    __syncthreads();

    // GEMM2 -> relu -> global (sliced layout: cslice = w, cw = l15)
    {
        bf16x8 A[2][4];
        #pragma unroll
        for (int ks = 0; ks < 4; ++ks)
            A[0][ks] = *(const bf16x8*)(hlds + (2 * ks + (lg >> 1)) * 4096 + l15 * 32 + (lg & 1) * 16);
        #pragma unroll
        for (int m = 0; m < 8; ++m) {
            int cur = m & 1, nxt = cur ^ 1;
            if (m < 7) {
                int row = (m + 1) * 16 + l15;
                #pragma unroll
                for (int ks = 0; ks < 4; ++ks)
                    A[nxt][ks] = *(const bf16x8*)(hlds + (2 * ks + (lg >> 1)) * 4096 + row * 32 + (lg & 1) * 16);
            }
            f32x4 acc = {0.f, 0.f, 0.f, 0.f};
            #pragma unroll
            for (int ks = 0; ks < 4; ++ks)
                acc = __builtin_amdgcn_mfma_f32_16x16x32_bf16(A[cur][ks], B2[ks], acc, 0, 0, 0);
            #pragma unroll
            for (int r = 0; r < 4; ++r) {
                int node = nbase + m * 16 + lg * 4 + r;
                if (node < N_NODES) {
                    float v = acc[r] + bias2; v = v > 0.f ? v : 0.f;
                    hout[((size_t)w * N_NODES + node) * 16 + l15] = f2bf(v);
                }
            }
        }
    }
}

// ---------------- fused head, M=128, slice-major LDS: 24 sub-tiles [128][32B] ----------------
__global__ __launch_bounds__(512, 2) void k_final(
    const unsigned short* __restrict__ h1, const unsigned short* __restrict__ h2,
    const unsigned short* __restrict__ h3,
    const unsigned short* __restrict__ l1t, const float* __restrict__ l1b,
    const unsigned short* __restrict__ l2t, const float* __restrict__ l2b,
    float* __restrict__ out) {
    extern __shared__ __align__(16) char lds[];    // 24 * 4096 = 96KB
    const int tid = threadIdx.x, lane = tid & 63, w = tid >> 6;
    const int l15 = lane & 15, lg = lane >> 4;
    const int nbase = blockIdx.x * 128;

    // stage: 96 chunks of 1KB, each = rows [rblk*32,+32) of one (part,slice) sub-tile
    #pragma unroll
    for (int i = 0; i < 12; ++i) {
        int c = w + i * 8;                  // chunk id [0,96)
        int g = c >> 2, rblk = c & 3;       // g: global slice [0,24)
        int part = g >> 3, slice = g & 7;
        int node = nbase + rblk * 32 + (lane >> 1);
        if (node >= N_NODES) node = 0;
        const unsigned short* hp = part == 0 ? h1 : (part == 1 ? h2 : h3);
        gld16(hp + ((size_t)slice * N_NODES + node) * 16 + (lane & 1) * 8,
              lds + c * 1024);
    }

    // preload lin1 B for ks=0,1 (2-deep)
    bf16x8 B[3][3];
    #pragma unroll
    for (int ot = 0; ot < 3; ++ot) {
        B[0][ot] = *(const bf16x8*)(l1t + ((size_t)((w * 3 + ot) * 12 + 0) * 64 + lane) * 8);
        B[1][ot] = *(const bf16x8*)(l1t + ((size_t)((w * 3 + ot) * 12 + 1) * 64 + lane) * 8);
    }
    __syncthreads();   // vmcnt(0) drains staging

    // lin1: wave w owns out cols [48w, 48w+48), 8 m-tiles
    f32x4 acc[8][3];
    #pragma unroll
    for (int m = 0; m < 8; ++m)
        #pragma unroll
        for (int ot = 0; ot < 3; ++ot) acc[m][ot] = {0.f, 0.f, 0.f, 0.f};
    {
        #pragma unroll
        for (int ks = 0; ks < 12; ++ks) {
            int cur = ks % 3;
            if (ks < 10) {
                int nx2 = (ks + 2) % 3;
                #pragma unroll
                for (int ot = 0; ot < 3; ++ot)
                    B[nx2][ot] = *(const bf16x8*)(l1t + ((size_t)((w * 3 + ot) * 12 + ks + 2) * 64 + lane) * 8);
            }
            bf16x8 A[8];
            #pragma unroll
            for (int m = 0; m < 8; ++m) {
                int row = m * 16 + l15;
                A[m] = *(const bf16x8*)(lds + (2 * ks + (lg >> 1)) * 4096 + row * 32 + (lg & 1) * 16);
            }
            #pragma unroll
            for (int ot = 0; ot < 3; ++ot)
                #pragma unroll
                for (int m = 0; m < 8; ++m)
                    acc[m][ot] = __builtin_amdgcn_mfma_f32_16x16x32_bf16(A[m], B[cur][ot], acc[m][ot], 0, 0, 0);
        }
    }
    __syncthreads();   // everyone done reading A-tile

    // relu + write hidden (bf16) into same LDS (wave's own sub-tiles g = w*3+ot)
    #pragma unroll
    for (int ot = 0; ot < 3; ++ot) {
        int c = (w * 3 + ot) * 16 + l15;
        float bias = l1b[c];
        #pragma unroll
        for (int m = 0; m < 8; ++m)
            #pragma unroll
            for (int r = 0; r < 4; ++r) {
                int row = m * 16 + lg * 4 + r;
                float v = acc[m][ot][r] + bias; v = v > 0.f ? v : 0.f;
                *(unsigned short*)(lds + (w * 3 + ot) * 4096 + row * 32 + l15 * 2) = f2bf(v);
            }
    }
    __syncthreads();

    // lin2: wave w owns rows [16w, 16w+16); B+A double-buffered over ks
    f32x4 acc2[3];
    #pragma unroll
    for (int ot = 0; ot < 3; ++ot) acc2[ot] = {0.f, 0.f, 0.f, 0.f};
    {
        const int row = w * 16 + l15;
        bf16x8 C2[2][3]; bf16x8 A2[2];
        #pragma unroll
        for (int ot = 0; ot < 3; ++ot)
            C2[0][ot] = *(const bf16x8*)(l2t + ((size_t)(ot * 12) * 64 + lane) * 8);
        A2[0] = *(const bf16x8*)(lds + (lg >> 1) * 4096 + row * 32 + (lg & 1) * 16);
        #pragma unroll
        for (int ks = 0; ks < 12; ++ks) {
            int cur = ks & 1, nxt = cur ^ 1;
            if (ks < 11) {
                #pragma unroll
                for (int ot = 0; ot < 3; ++ot)
                    C2[nxt][ot] = *(const bf16x8*)(l2t + ((size_t)(ot * 12 + ks + 1) * 64 + lane) * 8);
                A2[nxt] = *(const bf16x8*)(lds + (2 * (ks + 1) + (lg >> 1)) * 4096 + row * 32 + (lg & 1) * 16);
            }
            #pragma unroll
            for (int ot = 0; ot < 3; ++ot)
                acc2[ot] = __builtin_amdgcn_mfma_f32_16x16x32_bf16(A2[cur], C2[cur][ot], acc2[ot], 0, 0, 0);
        }
    }

    // bias + log_softmax over 40 classes
    int c0 = l15;
    #pragma unroll
    for (int r = 0; r < 4; ++r) {
        float v0 = acc2[0][r] + l2b[c0];
        float v1 = acc2[1][r] + l2b[c0 + 16];
        float v2 = (c0 < 8) ? (acc2[2][r] + l2b[c0 + 32]) : -1e30f;
        float mx = fmaxf(fmaxf(v0, v1), v2);
        for (int msk = 1; msk < 16; msk <<= 1) mx = fmaxf(mx, __shfl_xor(mx, msk));
        float s = __expf(v0 - mx) + __expf(v1 - mx) + ((c0 < 8) ? __expf(v2 - mx) : 0.f);
        for (int msk = 1; msk < 16; msk <<= 1) s += __shfl_xor(s, msk);
        float lse = mx + __logf(s);
        int node = nbase + w * 16 + lg * 4 + r;
        if (node < N_NODES) {
            out[(size_t)node * 40 + c0] = v0 - lse;
            out[(size_t)node * 40 + c0 + 16] = v1 - lse;
            if (c0 < 8) out[(size_t)node * 40 + c0 + 32] = v2 - lse;
        }
    }
}

extern "C" void kernel_launch(void* const* d_in, const int* in_sizes, int n_in,
                              void* d_out, int out_size, void* d_ws, size_t ws_size,
                              hipStream_t stream) {
    const float* x  = (const float*)d_in[0];
    const int*   ei = (const int*)d_in[1];
    const float* gw1[3] = {(const float*)d_in[2],  (const float*)d_in[6],  (const float*)d_in[10]};
    const float* gb1[3] = {(const float*)d_in[3],  (const float*)d_in[7],  (const float*)d_in[11]};
    const float* gw2[3] = {(const float*)d_in[4],  (const float*)d_in[8],  (const float*)d_in[12]};
    const float* gb2[3] = {(const float*)d_in[5],  (const float*)d_in[9],  (const float*)d_in[13]};
    const float* l1w = (const float*)d_in[14];
    const float* l1b = (const float*)d_in[15];
    const float* l2w = (const float*)d_in[16];
    const float* l2b = (const float*)d_in[17];
    float* out = (float*)d_out;

    char* p = (char*)d_ws;
    auto alloc = [&](size_t bytes) { char* q = p; p += (bytes + 255) & ~(size_t)255; return q; };
    int* rp   = (int*)alloc(4 * (N_NODES + 1));
    int* cnt  = (int*)alloc(4 * N_NODES);
    int* cur  = (int*)alloc(4 * N_NODES);
    int* bsum = (int*)alloc(4 * 256);
    int* colv = (int*)alloc(4 * (size_t)NEDGE);
    unsigned short* t  = (unsigned short*)alloc(2 * (size_t)N_NODES * 128);
    unsigned short* h1 = (unsigned short*)alloc(2 * (size_t)N_NODES * 128);
    unsigned short* h2 = (unsigned short*)alloc(2 * (size_t)N_NODES * 128);
    unsigned short* h3 = (unsigned short*)alloc(2 * (size_t)N_NODES * 128);
    unsigned short* xs = h3;   // alias: xs dead after layer-1 agg, h3 written in layer 3
    unsigned short* wt[6];
    for (int i = 0; i < 6; ++i) wt[i] = (unsigned short*)alloc(2 * 128 * 128);
    unsigned short* l1t = (unsigned short*)alloc(2 * 384 * 384);
    unsigned short* l2t = (unsigned short*)alloc(2 * 48 * 384);

    static bool attr_set = false;
    if (!attr_set) {
        hipFuncSetAttribute((const void*)k_final,
                            hipFuncAttributeMaxDynamicSharedMemorySize, 24 * 4096);
        attr_set = true;
    }

    const int nb = (N_NODES + 1023) / 1024;     // 98
    // CSR build
    hipMemsetAsync(cnt, 0, 4 * N_NODES, stream);
    k_countr<<<((NEDGE + 255) / 256) * FILL_SLICES, 256, 0, stream>>>(ei, cnt);
    k_scan1<<<nb, 256, 0, stream>>>(cnt, rp, bsum);
    k_scan2<<<1, 256, 0, stream>>>(bsum, nb);
    k_scan3<<<nb, 256, 0, stream>>>(rp, bsum, cur);
    k_fillr<<<((NEDGE + 255) / 256) * FILL_SLICES, 256, 0, stream>>>(ei, cur, colv);

    // weight prep (one dispatch, fragment-major bf16)
    k_wprep_all<<<(WPREP_TOT + 255) / 256, 256, 0, stream>>>(
        gw1[0], gw2[0], gw1[1], gw2[1], gw1[2], gw2[2], l1w, l2w, wt[0]);

    // x -> sliced bf16
    k_xprep<<<8 * ((N_NODES * 8 + 255) / 256), 256, 0, stream>>>(x, xs);

    const int gagg = ((N_NODES + AGG_NODES - 1) / AGG_NODES) * 8;
    const int gtile2 = (N_NODES + 127) / 128;
    // layer 1
    k_aggs<<<gagg, 256, 0, stream>>>(xs, t, rp, colv);
    k_mlp<<<gtile2, 512, 0, stream>>>(t, wt[0], gb1[0], wt[1], gb2[0], h1);
    // layer 2
    k_aggs<<<gagg, 256, 0, stream>>>(h1, t, rp, colv);
    k_mlp<<<gtile2, 512, 0, stream>>>(t, wt[2], gb1[1], wt[3], gb2[1], h2);
    // layer 3
    k_aggs<<<gagg, 256, 0, stream>>>(h2, t, rp, colv);
    k_mlp<<<gtile2, 512, 0, stream>>>(t, wt[4], gb1[2], wt[5], gb2[2], h3);
    // head
    k_final<<<gtile2, 512, 24 * 4096, stream>>>(h1, h2, h3, l1t, l1b, l2t, l2b, out);
}

// Round 11
// 496.460 us; speedup vs baseline: 1.0419x; 1.0419x over previous
//
#include <hip/hip_runtime.h>

#define N_NODES 100000
#define NEDGE   1600000
#define NHID    128
#define NCLASS  40

#define AGG_NODES 128
#define COLV_LDS  3072
#define FILL_SLICES 8
#define FILL_RANGE  12500   // N_NODES / FILL_SLICES
#define WPREP_TOT   264192  // 6*16384 + 147456 + 18432

using bf16x8 = __attribute__((ext_vector_type(8))) short;
using f32x4  = __attribute__((ext_vector_type(4))) float;

__device__ __forceinline__ float bf2f(unsigned short s) {
    unsigned u = ((unsigned)s) << 16; float f; __builtin_memcpy(&f, &u, 4); return f;
}
__device__ __forceinline__ unsigned short f2bf(float f) {
    unsigned u; __builtin_memcpy(&u, &f, 4);
    u = u + 0x7fffu + ((u >> 16) & 1u);          // RNE
    return (unsigned short)(u >> 16);
}

// global -> LDS direct (16B/lane). Dest: wave-uniform base; HW adds lane*16.
__device__ __forceinline__ void gld16(const void* g, void* l) {
    __builtin_amdgcn_global_load_lds(g, l, 16, 0, 0);
}

// ---------------- CSR build ----------------
__global__ __launch_bounds__(256) void k_countr(const int* __restrict__ ei, int* __restrict__ cnt) {
    int slice = blockIdx.x & 7;
    int e = (blockIdx.x >> 3) * 256 + threadIdx.x;
    if (e >= NEDGE) return;
    int d = ei[NEDGE + e];
    int lo = slice * FILL_RANGE;
    if (d >= lo && d < lo + FILL_RANGE) atomicAdd(&cnt[d], 1);
}

__global__ void k_scan1(const int* __restrict__ cnt, int* __restrict__ rp, int* __restrict__ bsum) {
    __shared__ int sh[256];
    int t = threadIdx.x, base = blockIdx.x * 1024;
    int v[4]; int s = 0;
    for (int k = 0; k < 4; ++k) { int i = base + t * 4 + k; v[k] = (i < N_NODES) ? cnt[i] : 0; s += v[k]; }
    sh[t] = s; __syncthreads();
    for (int off = 1; off < 256; off <<= 1) {
        int x = (t >= off) ? sh[t - off] : 0;
        __syncthreads();
        sh[t] += x;
        __syncthreads();
    }
    int excl = sh[t] - s;
    for (int k = 0; k < 4; ++k) { int i = base + t * 4 + k; if (i < N_NODES) rp[i] = excl; excl += v[k]; }
    if (t == 255) bsum[blockIdx.x] = sh[255];
}

__global__ void k_scan2(int* __restrict__ bsum, int nb) {
    __shared__ int sh[256];
    int t = threadIdx.x;
    int v = (t < nb) ? bsum[t] : 0;
    sh[t] = v; __syncthreads();
    for (int off = 1; off < 256; off <<= 1) {
        int x = (t >= off) ? sh[t - off] : 0;
        __syncthreads();
        sh[t] += x;
        __syncthreads();
    }
    if (t < nb) bsum[t] = sh[t] - v;   // exclusive block offsets
}

__global__ void k_scan3(int* __restrict__ rp, const int* __restrict__ bsum, int* __restrict__ cur) {
    int base = blockIdx.x * 1024;
    int off = bsum[blockIdx.x];
    for (int k = 0; k < 4; ++k) {
        int i = base + threadIdx.x * 4 + k;
        if (i < N_NODES) { int v = rp[i] + off; rp[i] = v; cur[i] = v; }
    }
    if (blockIdx.x == 0 && threadIdx.x == 0) rp[N_NODES] = NEDGE;
}

__global__ __launch_bounds__(256) void k_fillr(const int* __restrict__ ei,
                                               int* __restrict__ cur, int* __restrict__ colv) {
    int slice = blockIdx.x & 7;
    int e = (blockIdx.x >> 3) * 256 + threadIdx.x;
    if (e >= NEDGE) return;
    int d = ei[NEDGE + e];
    int lo = slice * FILL_RANGE;
    if (d >= lo && d < lo + FILL_RANGE) {
        int p = atomicAdd(&cur[d], 1);
        colv[p] = ei[e];
    }
}

// ---------------- weight prep: ALL weights in one dispatch, fragment-major bf16 ----------------
__global__ void k_wprep_all(const float* __restrict__ g0, const float* __restrict__ g1,
                            const float* __restrict__ g2, const float* __restrict__ g3,
                            const float* __restrict__ g4, const float* __restrict__ g5,
                            const float* __restrict__ l1w, const float* __restrict__ l2w,
                            unsigned short* __restrict__ dst) {
    int idx = blockIdx.x * 256 + threadIdx.x;
    if (idx >= WPREP_TOT) return;
    const float* w; int local, K, O;
    if (idx < 98304) {
        int r = idx >> 14; local = idx & 16383; K = 128; O = 128;
        w = r == 0 ? g0 : r == 1 ? g1 : r == 2 ? g2 : r == 3 ? g3 : r == 4 ? g4 : g5;
    } else if (idx < 245760) {
        local = idx - 98304; K = 384; O = 384; w = l1w;
    } else {
        local = idx - 245760; K = 384; O = 40; w = l2w;
    }
    int kss = K >> 5;
    int e = local & 7, lane = (local >> 3) & 63, rest = local >> 9;
    int ks = rest % kss, ot = rest / kss;
    int c = ot * 16 + (lane & 15);
    int k = ks * 32 + (lane >> 4) * 8 + e;
    float v = (c < O) ? w[k * O + c] : 0.f;
    dst[idx] = f2bf(v);
}

// ---------------- x -> sliced bf16 layout [8][N][16] ----------------
__global__ void k_xprep(const float* __restrict__ x, unsigned short* __restrict__ xs) {
    int s = blockIdx.x & 7;
    int rest = (blockIdx.x >> 3) * 256 + threadIdx.x;
    if (rest >= N_NODES * 8) return;
    int n = rest >> 3, wrd = rest & 7;
    float2 v = *(const float2*)(x + (size_t)n * 128 + s * 16 + wrd * 2);
    ((unsigned*)xs)[(size_t)s * N_NODES * 8 + rest] =
        (unsigned)f2bf(v.x) | ((unsigned)f2bf(v.y) << 16);
}

// ---------------- aggregation, sliced + LDS colv + 8-deep gather MLP ----------------
__device__ __forceinline__ void acc8(float* acc, uint4 f, float m) {
    unsigned u[4] = {f.x, f.y, f.z, f.w};
    for (int d = 0; d < 4; ++d) {
        acc[2 * d]     = fmaf(m, bf2f((unsigned short)u[d]), acc[2 * d]);
        acc[2 * d + 1] = fmaf(m, bf2f((unsigned short)(u[d] >> 16)), acc[2 * d + 1]);
    }
}

__global__ __launch_bounds__(256) void k_aggs(const unsigned short* __restrict__ feat,
                                              unsigned short* __restrict__ tout,
                                              const int* __restrict__ rp,
                                              const int* __restrict__ colv) {
    __shared__ int scol[COLV_LDS + 8];
    __shared__ int srp[AGG_NODES + 1];
    const int s = blockIdx.x & 7;
    const int chunk = blockIdx.x >> 3;
    const int tid = threadIdx.x;
    const int nbase = chunk * AGG_NODES;

    for (int i = tid; i <= AGG_NODES; i += 256) {
        int n = nbase + i;
        srp[i] = rp[n <= N_NODES ? n : N_NODES];
    }
    __syncthreads();
    const int ebase = srp[0];
    const int ecount = srp[AGG_NODES] - ebase;
    const int elds = ecount < COLV_LDS ? ecount : COLV_LDS;
    for (int i = tid; i < elds; i += 256) scol[i] = colv[ebase + i];
    if (tid < 8) scol[elds + tid] = 0;
    __syncthreads();

    const unsigned* fs = (const unsigned*)feat + (size_t)s * N_NODES * 8;
    unsigned* ts = (unsigned*)tout + (size_t)s * N_NODES * 8;

    const int sub = tid >> 1, half = tid & 1;
    const int node = nbase + sub;
    if (node >= N_NODES) return;
    const int off = half * 4;
    const int e0 = srp[sub] - ebase, e1 = srp[sub + 1] - ebase;

    float acc[8];
    {
        uint4 a = *(const uint4*)(fs + (size_t)node * 8 + off);
        unsigned u[4] = {a.x, a.y, a.z, a.w};
        for (int d = 0; d < 4; ++d) {
            acc[2 * d]     = bf2f((unsigned short)u[d]);
            acc[2 * d + 1] = bf2f((unsigned short)(u[d] >> 16));
        }
    }

    if (ecount <= COLV_LDS) {
        int e = e0;
        const int efull = e0 + ((e1 - e0) & ~7);
        for (; e < efull; e += 8) {
            int j[8];
            #pragma unroll
            for (int k = 0; k < 8; ++k) j[k] = scol[e + k];
            uint4 f[8];
            #pragma unroll
            for (int k = 0; k < 8; ++k)
                f[k] = *(const uint4*)(fs + (size_t)j[k] * 8 + off);
            #pragma unroll
            for (int k = 0; k < 8; ++k) acc8(acc, f[k], 1.f);
        }
        if (e < e1) {
            int j[8]; float m[8];
            #pragma unroll
            for (int k = 0; k < 8; ++k) {
                int ee = e + k;
                bool v = ee < e1;
                j[k] = v ? scol[ee] : node;
                m[k] = v ? 1.f : 0.f;
            }
            uint4 f[8];
            #pragma unroll
            for (int k = 0; k < 8; ++k)
                f[k] = *(const uint4*)(fs + (size_t)j[k] * 8 + off);
            #pragma unroll
            for (int k = 0; k < 8; ++k) acc8(acc, f[k], m[k]);
        }
    } else {
        for (int e = e0; e < e1; e += 8) {
            int j[8]; float m[8];
            #pragma unroll
            for (int k = 0; k < 8; ++k) {
                int ee = e + k;
                bool v = ee < e1;
                int idx = ee < COLV_LDS ? scol[ee] : colv[ebase + ee];
                j[k] = v ? idx : node;
                m[k] = v ? 1.f : 0.f;
            }
            uint4 f[8];
            #pragma unroll
            for (int k = 0; k < 8; ++k)
                f[k] = *(const uint4*)(fs + (size_t)j[k] * 8 + off);
            #pragma unroll
            for (int k = 0; k < 8; ++k) acc8(acc, f[k], m[k]);
        }
    }

    uint4 o;
    o.x = (unsigned)f2bf(acc[0]) | ((unsigned)f2bf(acc[1]) << 16);
    o.y = (unsigned)f2bf(acc[2]) | ((unsigned)f2bf(acc[3]) << 16);
    o.z = (unsigned)f2bf(acc[4]) | ((unsigned)f2bf(acc[5]) << 16);
    o.w = (unsigned)f2bf(acc[6]) | ((unsigned)f2bf(acc[7]) << 16);
    *(uint4*)(ts + (size_t)node * 8 + off) = o;
}

// ---------------- fused GIN MLP, M=128, slice-major sub-tiles + half-XOR ----------------
// LDS sub-tile [slice][128 rows][32B]; 16B-half position = h ^ ((row>>2)&1) -> conflict-free
// 16-row column reads. Staging keeps linear dest; source half pre-XORed (contiguity kept:
// the two 16B halves of one node's 32B merely swap).
__global__ __launch_bounds__(512) void k_mlp(
    const unsigned short* __restrict__ tin,
    const unsigned short* __restrict__ w1t, const float* __restrict__ b1,
    const unsigned short* __restrict__ w2t, const float* __restrict__ b2,
    unsigned short* __restrict__ hout) {
    __shared__ __align__(16) char tlds[8 * 4096];
    __shared__ __align__(16) char hlds[8 * 4096];
    const int tid = threadIdx.x, lane = tid & 63, w = tid >> 6;
    const int l15 = lane & 15, lg = lane >> 4;
    const int nbase = blockIdx.x * 128;
    const int rxor = (l15 >> 2) & 1;    // (row>>2)&1 for row = m*16 + l15

    // stage t tile: 32 chunks of 1KB (rows [rblk*32,+32) of slice s), source-half XORed
    #pragma unroll
    for (int i = 0; i < 4; ++i) {
        int c = w + i * 8;                 // chunk id [0,32)
        int s = c >> 2, rblk = c & 3;
        int node = nbase + rblk * 32 + (lane >> 1);
        if (node >= N_NODES) node = 0;
        int hsrc = (lane & 1) ^ ((lane >> 3) & 1);
        gld16(tin + ((size_t)s * N_NODES + node) * 16 + hsrc * 8,
              tlds + c * 1024);
    }

    // preload B1 AND B2 (wave w owns ot = w); B2 latency hides behind GEMM1
    bf16x8 B1[4], B2[4];
    const int col = w * 16 + l15;
    const float bias1 = b1[col], bias2 = b2[col];
    #pragma unroll
    for (int ks = 0; ks < 4; ++ks) {
        B1[ks] = *(const bf16x8*)(w1t + ((size_t)(w * 4 + ks) * 64 + lane) * 8);
        B2[ks] = *(const bf16x8*)(w2t + ((size_t)(w * 4 + ks) * 64 + lane) * 8);
    }
    __syncthreads();   // vmcnt(0) drains staging

    // GEMM1 -> relu -> hlds
    {
        const int hoff = (((lg & 1) ^ rxor) << 4) + ((lg >> 1) ? 4096 : 0);
        bf16x8 A[2][4];
        #pragma unroll
        for (int ks = 0; ks < 4; ++ks)
            A[0][ks] = *(const bf16x8*)(tlds + 2 * ks * 4096 + l15 * 32 + hoff);
        #pragma unroll
        for (int m = 0; m < 8; ++m) {
            int cur = m & 1, nxt = cur ^ 1;
            if (m < 7) {
                int row = (m + 1) * 16 + l15;
                #pragma unroll
                for (int ks = 0; ks < 4; ++ks)
                    A[nxt][ks] = *(const bf16x8*)(tlds + 2 * ks * 4096 + row * 32 + hoff);
            }
            f32x4 acc = {0.f, 0.f, 0.f, 0.f};
            #pragma unroll
            for (int ks = 0; ks < 4; ++ks)
                acc = __builtin_amdgcn_mfma_f32_16x16x32_bf16(A[cur][ks], B1[ks], acc, 0, 0, 0);
            #pragma unroll
            for (int r = 0; r < 4; ++r) {
                int row = m * 16 + lg * 4 + r;
                float v = acc[r] + bias1; v = v > 0.f ? v : 0.f;
                *(unsigned short*)(hlds + w * 4096 + row * 32 +
                                   ((l15 * 2) ^ ((((row >> 2) & 1)) << 4))) = f2bf(v);
            }
        }
    }
    __syncthreads();

    // GEMM2 -> relu -> global (sliced layout: cslice = w, cw = l15)
    {
        const int hoff = (((lg & 1) ^ rxor) << 4) + ((lg >> 1) ? 4096 : 0);
        bf16x8 A[2][4];
        #pragma unroll
        for (int ks = 0; ks < 4; ++ks)
            A[0][ks] = *(const bf16x8*)(hlds + 2 * ks * 4096 + l15 * 32 + hoff);
        #pragma unroll
        for (int m = 0; m < 8; ++m) {
            int cur = m & 1, nxt = cur ^ 1;
            if (m < 7) {
                int row = (m + 1) * 16 + l15;
                #pragma unroll
                for (int ks = 0; ks < 4; ++ks)
                    A[nxt][ks] = *(const bf16x8*)(hlds + 2 * ks * 4096 + row * 32 + hoff);
            }
            f32x4 acc = {0.f, 0.f, 0.f, 0.f};
            #pragma unroll
            for (int ks = 0; ks < 4; ++ks)
                acc = __builtin_amdgcn_mfma_f32_16x16x32_bf16(A[cur][ks], B2[ks], acc, 0, 0, 0);
            #pragma unroll
            for (int r = 0; r < 4; ++r) {
                int node = nbase + m * 16 + lg * 4 + r;
                if (node < N_NODES) {
                    float v = acc[r] + bias2; v = v > 0.f ? v : 0.f;
                    hout[((size_t)w * N_NODES + node) * 16 + l15] = f2bf(v);
                }
            }
        }
    }
}

// ---------------- fused head, M=64, 48KB LDS -> 2 blocks/CU ----------------
// 512 threads (8 waves); 24 sub-tiles [64][32B] (2KB each). Wave w owns 48 lin1 cols (3 ot)
// over 4 m-tiles. Half-XOR layout as in k_mlp. lin2+softmax on waves 0-3 only.
__global__ __launch_bounds__(512, 4) void k_final(
    const unsigned short* __restrict__ h1, const unsigned short* __restrict__ h2,
    const unsigned short* __restrict__ h3,
    const unsigned short* __restrict__ l1t, const float* __restrict__ l1b,
    const unsigned short* __restrict__ l2t, const float* __restrict__ l2b,
    float* __restrict__ out) {
    __shared__ __align__(16) char lds[24 * 2048];   // 48KB
    const int tid = threadIdx.x, lane = tid & 63, w = tid >> 6;
    const int l15 = lane & 15, lg = lane >> 4;
    const int nbase = blockIdx.x * 64;
    const int rxor = (l15 >> 2) & 1;

    // stage: 48 chunks of 1KB; chunk c: sub-tile g=c>>1, rows [(c&1)*32,+32)
    #pragma unroll
    for (int i = 0; i < 6; ++i) {
        int c = w + i * 8;                  // chunk id [0,48)
        int g = c >> 1, rblk = c & 1;       // g: global slice [0,24)
        int part = g >> 3, slice = g & 7;
        int node = nbase + rblk * 32 + (lane >> 1);
        if (node >= N_NODES) node = 0;
        int hsrc = (lane & 1) ^ ((lane >> 3) & 1);
        const unsigned short* hp = part == 0 ? h1 : (part == 1 ? h2 : h3);
        gld16(hp + ((size_t)slice * N_NODES + node) * 16 + hsrc * 8,
              lds + c * 1024);
    }

    // preload lin1 B for ks=0
    bf16x8 B[2][3];
    #pragma unroll
    for (int ot = 0; ot < 3; ++ot)
        B[0][ot] = *(const bf16x8*)(l1t + ((size_t)((w * 3 + ot) * 12) * 64 + lane) * 8);
    __syncthreads();   // vmcnt(0) drains staging

    // lin1: wave w owns out cols [48w, 48w+48), 4 m-tiles; B double-buffered
    f32x4 acc[4][3];
    #pragma unroll
    for (int m = 0; m < 4; ++m)
        #pragma unroll
        for (int ot = 0; ot < 3; ++ot) acc[m][ot] = {0.f, 0.f, 0.f, 0.f};
    {
        const int hoff = (((lg & 1) ^ rxor) << 4) + ((lg >> 1) ? 2048 : 0);
        #pragma unroll
        for (int ks = 0; ks < 12; ++ks) {
            int cur = ks & 1, nxt = cur ^ 1;
            if (ks < 11) {
                #pragma unroll
                for (int ot = 0; ot < 3; ++ot)
                    B[nxt][ot] = *(const bf16x8*)(l1t + ((size_t)((w * 3 + ot) * 12 + ks + 1) * 64 + lane) * 8);
            }
            bf16x8 A[4];
            #pragma unroll
            for (int m = 0; m < 4; ++m) {
                int row = m * 16 + l15;
                A[m] = *(const bf16x8*)(lds + 2 * ks * 2048 + row * 32 + hoff);
            }
            #pragma unroll
            for (int ot = 0; ot < 3; ++ot)
                #pragma unroll
                for (int m = 0; m < 4; ++m)
                    acc[m][ot] = __builtin_amdgcn_mfma_f32_16x16x32_bf16(A[m], B[cur][ot], acc[m][ot], 0, 0, 0);
        }
    }
    __syncthreads();   // everyone done reading A-tile

    // relu + write hidden (bf16) into same LDS (wave's own sub-tiles g = w*3+ot)
    #pragma unroll
    for (int ot = 0; ot < 3; ++ot) {
        int c = (w * 3 + ot) * 16 + l15;
        float bias = l1b[c];
        #pragma unroll
        for (int m = 0; m < 4; ++m)
            #pragma unroll
            for (int r = 0; r < 4; ++r) {
                int row = m * 16 + lg * 4 + r;
                float v = acc[m][ot][r] + bias; v = v > 0.f ? v : 0.f;
                *(unsigned short*)(lds + (w * 3 + ot) * 2048 + row * 32 +
                                   ((l15 * 2) ^ ((((row >> 2) & 1)) << 4))) = f2bf(v);
            }
    }
    __syncthreads();

    // lin2 + softmax: waves 0-3 own rows [16w,+16) of the 64
    if (w < 4) {
        f32x4 acc2[3];
        #pragma unroll
        for (int ot = 0; ot < 3; ++ot) acc2[ot] = {0.f, 0.f, 0.f, 0.f};
        {
            const int row = w * 16 + l15;
            const int hoff = (((lg & 1) ^ rxor) << 4) + ((lg >> 1) ? 2048 : 0);
            bf16x8 C2[2][3];
            #pragma unroll
            for (int ot = 0; ot < 3; ++ot)
                C2[0][ot] = *(const bf16x8*)(l2t + ((size_t)(ot * 12) * 64 + lane) * 8);
            #pragma unroll
            for (int ks = 0; ks < 12; ++ks) {
                int cur = ks & 1, nxt = cur ^ 1;
                if (ks < 11) {
                    #pragma unroll
                    for (int ot = 0; ot < 3; ++ot)
                        C2[nxt][ot] = *(const bf16x8*)(l2t + ((size_t)(ot * 12 + ks + 1) * 64 + lane) * 8);
                }
                bf16x8 A2 = *(const bf16x8*)(lds + 2 * ks * 2048 + row * 32 + hoff);
                #pragma unroll
                for (int ot = 0; ot < 3; ++ot)
                    acc2[ot] = __builtin_amdgcn_mfma_f32_16x16x32_bf16(A2, C2[cur][ot], acc2[ot], 0, 0, 0);
            }
        }

        // bias + log_softmax over 40 classes
        int c0 = l15;
        #pragma unroll
        for (int r = 0; r < 4; ++r) {
            float v0 = acc2[0][r] + l2b[c0];
            float v1 = acc2[1][r] + l2b[c0 + 16];
            float v2 = (c0 < 8) ? (acc2[2][r] + l2b[c0 + 32]) : -1e30f;
            float mx = fmaxf(fmaxf(v0, v1), v2);
            for (int msk = 1; msk < 16; msk <<= 1) mx = fmaxf(mx, __shfl_xor(mx, msk));
            float s = __expf(v0 - mx) + __expf(v1 - mx) + ((c0 < 8) ? __expf(v2 - mx) : 0.f);
            for (int msk = 1; msk < 16; msk <<= 1) s += __shfl_xor(s, msk);
            float lse = mx + __logf(s);
            int node = nbase + w * 16 + lg * 4 + r;
            if (node < N_NODES) {
                out[(size_t)node * 40 + c0] = v0 - lse;
                out[(size_t)node * 40 + c0 + 16] = v1 - lse;
                if (c0 < 8) out[(size_t)node * 40 + c0 + 32] = v2 - lse;
            }
        }
    }
}

extern "C" void kernel_launch(void* const* d_in, const int* in_sizes, int n_in,
                              void* d_out, int out_size, void* d_ws, size_t ws_size,
                              hipStream_t stream) {
    const float* x  = (const float*)d_in[0];
    const int*   ei = (const int*)d_in[1];
    const float* gw1[3] = {(const float*)d_in[2],  (const float*)d_in[6],  (const float*)d_in[10]};
    const float* gb1[3] = {(const float*)d_in[3],  (const float*)d_in[7],  (const float*)d_in[11]};
    const float* gw2[3] = {(const float*)d_in[4],  (const float*)d_in[8],  (const float*)d_in[12]};
    const float* gb2[3] = {(const float*)d_in[5],  (const float*)d_in[9],  (const float*)d_in[13]};
    const float* l1w = (const float*)d_in[14];
    const float* l1b = (const float*)d_in[15];
    const float* l2w = (const float*)d_in[16];
    const float* l2b = (const float*)d_in[17];
    float* out = (float*)d_out;

    char* p = (char*)d_ws;
    auto alloc = [&](size_t bytes) { char* q = p; p += (bytes + 255) & ~(size_t)255; return q; };
    int* rp   = (int*)alloc(4 * (N_NODES + 1));
    int* cnt  = (int*)alloc(4 * N_NODES);
    int* cur  = (int*)alloc(4 * N_NODES);
    int* bsum = (int*)alloc(4 * 256);
    int* colv = (int*)alloc(4 * (size_t)NEDGE);
    unsigned short* t  = (unsigned short*)alloc(2 * (size_t)N_NODES * 128);
    unsigned short* h1 = (unsigned short*)alloc(2 * (size_t)N_NODES * 128);
    unsigned short* h2 = (unsigned short*)alloc(2 * (size_t)N_NODES * 128);
    unsigned short* h3 = (unsigned short*)alloc(2 * (size_t)N_NODES * 128);
    unsigned short* xs = h3;   // alias: xs dead after layer-1 agg, h3 written in layer 3
    unsigned short* wt[6];
    for (int i = 0; i < 6; ++i) wt[i] = (unsigned short*)alloc(2 * 128 * 128);
    unsigned short* l1t = (unsigned short*)alloc(2 * 384 * 384);
    unsigned short* l2t = (unsigned short*)alloc(2 * 48 * 384);

    const int nb = (N_NODES + 1023) / 1024;     // 98
    // CSR build
    hipMemsetAsync(cnt, 0, 4 * N_NODES, stream);
    k_countr<<<((NEDGE + 255) / 256) * FILL_SLICES, 256, 0, stream>>>(ei, cnt);
    k_scan1<<<nb, 256, 0, stream>>>(cnt, rp, bsum);
    k_scan2<<<1, 256, 0, stream>>>(bsum, nb);
    k_scan3<<<nb, 256, 0, stream>>>(rp, bsum, cur);
    k_fillr<<<((NEDGE + 255) / 256) * FILL_SLICES, 256, 0, stream>>>(ei, cur, colv);

    // weight prep (one dispatch, fragment-major bf16)
    k_wprep_all<<<(WPREP_TOT + 255) / 256, 256, 0, stream>>>(
        gw1[0], gw2[0], gw1[1], gw2[1], gw1[2], gw2[2], l1w, l2w, wt[0]);

    // x -> sliced bf16
    k_xprep<<<8 * ((N_NODES * 8 + 255) / 256), 256, 0, stream>>>(x, xs);

    const int gagg = ((N_NODES + AGG_NODES - 1) / AGG_NODES) * 8;
    const int gtile2 = (N_NODES + 127) / 128;
    const int gtile1 = (N_NODES + 63) / 64;
    // layer 1
    k_aggs<<<gagg, 256, 0, stream>>>(xs, t, rp, colv);
    k_mlp<<<gtile2, 512, 0, stream>>>(t, wt[0], gb1[0], wt[1], gb2[0], h1);
    // layer 2
    k_aggs<<<gagg, 256, 0, stream>>>(h1, t, rp, colv);
    k_mlp<<<gtile2, 512, 0, stream>>>(t, wt[2], gb1[1], wt[3], gb2[1], h2);
    // layer 3
    k_aggs<<<gagg, 256, 0, stream>>>(h2, t, rp, colv);
    k_mlp<<<gtile2, 512, 0, stream>>>(t, wt[4], gb1[2], wt[5], gb2[2], h3);
    // head
    k_final<<<gtile1, 512, 0, stream>>>(h1, h2, h3, l1t, l1b, l2t, l2b, out);
}

// Round 12
// 475.382 us; speedup vs baseline: 1.0881x; 1.0443x over previous
//
#include <hip/hip_runtime.h>

#define N_NODES 100000
#define NEDGE   1600000
#define NHID    128
#define NCLASS  40

#define AGG_NODES 128
#define COLV_LDS  3072
#define FILL_SLICES 8
#define FILL_RANGE  12500   // N_NODES / FILL_SLICES
#define WPREP_TOT   264192  // 6*16384 + 147456 + 18432

using bf16x8 = __attribute__((ext_vector_type(8))) short;
using f32x4  = __attribute__((ext_vector_type(4))) float;

__device__ __forceinline__ float bf2f(unsigned short s) {
    unsigned u = ((unsigned)s) << 16; float f; __builtin_memcpy(&f, &u, 4); return f;
}
__device__ __forceinline__ unsigned short f2bf(float f) {
    unsigned u; __builtin_memcpy(&u, &f, 4);
    u = u + 0x7fffu + ((u >> 16) & 1u);          // RNE
    return (unsigned short)(u >> 16);
}

// global -> LDS direct (16B/lane). Dest: wave-uniform base; HW adds lane*16.
__device__ __forceinline__ void gld16(const void* g, void* l) {
    __builtin_amdgcn_global_load_lds(g, l, 16, 0, 0);
}

// ---------------- CSR build ----------------
__global__ __launch_bounds__(256) void k_countr(const int* __restrict__ ei, int* __restrict__ cnt) {
    int slice = blockIdx.x & 7;
    int e = (blockIdx.x >> 3) * 256 + threadIdx.x;
    if (e >= NEDGE) return;
    int d = ei[NEDGE + e];
    int lo = slice * FILL_RANGE;
    if (d >= lo && d < lo + FILL_RANGE) atomicAdd(&cnt[d], 1);
}

__global__ void k_scan1(const int* __restrict__ cnt, int* __restrict__ rp, int* __restrict__ bsum) {
    __shared__ int sh[256];
    int t = threadIdx.x, base = blockIdx.x * 1024;
    int v[4]; int s = 0;
    for (int k = 0; k < 4; ++k) { int i = base + t * 4 + k; v[k] = (i < N_NODES) ? cnt[i] : 0; s += v[k]; }
    sh[t] = s; __syncthreads();
    for (int off = 1; off < 256; off <<= 1) {
        int x = (t >= off) ? sh[t - off] : 0;
        __syncthreads();
        sh[t] += x;
        __syncthreads();
    }
    int excl = sh[t] - s;
    for (int k = 0; k < 4; ++k) { int i = base + t * 4 + k; if (i < N_NODES) rp[i] = excl; excl += v[k]; }
    if (t == 255) bsum[blockIdx.x] = sh[255];
}

__global__ void k_scan2(int* __restrict__ bsum, int nb) {
    __shared__ int sh[256];
    int t = threadIdx.x;
    int v = (t < nb) ? bsum[t] : 0;
    sh[t] = v; __syncthreads();
    for (int off = 1; off < 256; off <<= 1) {
        int x = (t >= off) ? sh[t - off] : 0;
        __syncthreads();
        sh[t] += x;
        __syncthreads();
    }
    if (t < nb) bsum[t] = sh[t] - v;   // exclusive block offsets
}

__global__ void k_scan3(int* __restrict__ rp, const int* __restrict__ bsum, int* __restrict__ cur) {
    int base = blockIdx.x * 1024;
    int off = bsum[blockIdx.x];
    for (int k = 0; k < 4; ++k) {
        int i = base + threadIdx.x * 4 + k;
        if (i < N_NODES) { int v = rp[i] + off; rp[i] = v; cur[i] = v; }
    }
    if (blockIdx.x == 0 && threadIdx.x == 0) rp[N_NODES] = NEDGE;
}

__global__ __launch_bounds__(256) void k_fillr(const int* __restrict__ ei,
                                               int* __restrict__ cur, int* __restrict__ colv) {
    int slice = blockIdx.x & 7;
    int e = (blockIdx.x >> 3) * 256 + threadIdx.x;
    if (e >= NEDGE) return;
    int d = ei[NEDGE + e];
    int lo = slice * FILL_RANGE;
    if (d >= lo && d < lo + FILL_RANGE) {
        int p = atomicAdd(&cur[d], 1);
        colv[p] = ei[e];
    }
}

// ---------------- weight prep: ALL weights in one dispatch, fragment-major bf16 ----------------
__global__ void k_wprep_all(const float* __restrict__ g0, const float* __restrict__ g1,
                            const float* __restrict__ g2, const float* __restrict__ g3,
                            const float* __restrict__ g4, const float* __restrict__ g5,
                            const float* __restrict__ l1w, const float* __restrict__ l2w,
                            unsigned short* __restrict__ dst) {
    int idx = blockIdx.x * 256 + threadIdx.x;
    if (idx >= WPREP_TOT) return;
    const float* w; int local, K, O;
    if (idx < 98304) {
        int r = idx >> 14; local = idx & 16383; K = 128; O = 128;
        w = r == 0 ? g0 : r == 1 ? g1 : r == 2 ? g2 : r == 3 ? g3 : r == 4 ? g4 : g5;
    } else if (idx < 245760) {
        local = idx - 98304; K = 384; O = 384; w = l1w;
    } else {
        local = idx - 245760; K = 384; O = 40; w = l2w;
    }
    int kss = K >> 5;
    int e = local & 7, lane = (local >> 3) & 63, rest = local >> 9;
    int ks = rest % kss, ot = rest / kss;
    int c = ot * 16 + (lane & 15);
    int k = ks * 32 + (lane >> 4) * 8 + e;
    float v = (c < O) ? w[k * O + c] : 0.f;
    dst[idx] = f2bf(v);
}

// ---------------- x -> sliced bf16 layout [4][N][32] ----------------
__global__ void k_xprep(const float* __restrict__ x, unsigned short* __restrict__ xs) {
    int s = blockIdx.x & 3;
    int rest = (blockIdx.x >> 2) * 256 + threadIdx.x;   // dword index within slice, N*16
    if (rest >= N_NODES * 16) return;
    int n = rest >> 4, wrd = rest & 15;
    float2 v = *(const float2*)(x + (size_t)n * 128 + s * 32 + wrd * 2);
    ((unsigned*)xs)[(size_t)s * N_NODES * 16 + rest] =
        (unsigned)f2bf(v.x) | ((unsigned)f2bf(v.y) << 16);
}

// ---------------- aggregation: 4 slices x 64B rows, 4 lanes/edge, 8-deep gather ----------------
__device__ __forceinline__ void acc8(float* acc, uint4 f, float m) {
    unsigned u[4] = {f.x, f.y, f.z, f.w};
    for (int d = 0; d < 4; ++d) {
        acc[2 * d]     = fmaf(m, bf2f((unsigned short)u[d]), acc[2 * d]);
        acc[2 * d + 1] = fmaf(m, bf2f((unsigned short)(u[d] >> 16)), acc[2 * d + 1]);
    }
}

__global__ __launch_bounds__(512) void k_aggs(const unsigned short* __restrict__ feat,
                                              unsigned short* __restrict__ tout,
                                              const int* __restrict__ rp,
                                              const int* __restrict__ colv) {
    __shared__ int scol[COLV_LDS + 8];
    __shared__ int srp[AGG_NODES + 1];
    const int s = blockIdx.x & 3;
    const int chunk = blockIdx.x >> 2;
    const int tid = threadIdx.x;
    const int nbase = chunk * AGG_NODES;

    for (int i = tid; i <= AGG_NODES; i += 512) {
        int n = nbase + i;
        srp[i] = rp[n <= N_NODES ? n : N_NODES];
    }
    __syncthreads();
    const int ebase = srp[0];
    const int ecount = srp[AGG_NODES] - ebase;
    const int elds = ecount < COLV_LDS ? ecount : COLV_LDS;
    for (int i = tid; i < elds; i += 512) scol[i] = colv[ebase + i];
    if (tid < 8) scol[elds + tid] = 0;
    __syncthreads();

    const unsigned* fs = (const unsigned*)feat + (size_t)s * N_NODES * 16;
    unsigned* ts = (unsigned*)tout + (size_t)s * N_NODES * 16;

    const int sub = tid >> 2, q = tid & 3;      // 4 lanes per node, q*16B of the 64B row
    const int node = nbase + sub;
    if (node >= N_NODES) return;
    const int off = q * 4;                       // dwords
    const int e0 = srp[sub] - ebase, e1 = srp[sub + 1] - ebase;

    float acc[8];
    {
        uint4 a = *(const uint4*)(fs + (size_t)node * 16 + off);
        unsigned u[4] = {a.x, a.y, a.z, a.w};
        for (int d = 0; d < 4; ++d) {
            acc[2 * d]     = bf2f((unsigned short)u[d]);
            acc[2 * d + 1] = bf2f((unsigned short)(u[d] >> 16));
        }
    }

    if (ecount <= COLV_LDS) {
        int e = e0;
        const int efull = e0 + ((e1 - e0) & ~7);
        for (; e < efull; e += 8) {
            int j[8];
            #pragma unroll
            for (int k = 0; k < 8; ++k) j[k] = scol[e + k];
            uint4 f[8];
            #pragma unroll
            for (int k = 0; k < 8; ++k)
                f[k] = *(const uint4*)(fs + (size_t)j[k] * 16 + off);
            #pragma unroll
            for (int k = 0; k < 8; ++k) acc8(acc, f[k], 1.f);
        }
        if (e < e1) {
            int j[8]; float m[8];
            #pragma unroll
            for (int k = 0; k < 8; ++k) {
                int ee = e + k;
                bool v = ee < e1;
                j[k] = v ? scol[ee] : node;
                m[k] = v ? 1.f : 0.f;
            }
            uint4 f[8];
            #pragma unroll
            for (int k = 0; k < 8; ++k)
                f[k] = *(const uint4*)(fs + (size_t)j[k] * 16 + off);
            #pragma unroll
            for (int k = 0; k < 8; ++k) acc8(acc, f[k], m[k]);
        }
    } else {
        for (int e = e0; e < e1; e += 8) {
            int j[8]; float m[8];
            #pragma unroll
            for (int k = 0; k < 8; ++k) {
                int ee = e + k;
                bool v = ee < e1;
                int idx = ee < COLV_LDS ? scol[ee] : colv[ebase + ee];
                j[k] = v ? idx : node;
                m[k] = v ? 1.f : 0.f;
            }
            uint4 f[8];
            #pragma unroll
            for (int k = 0; k < 8; ++k)
                f[k] = *(const uint4*)(fs + (size_t)j[k] * 16 + off);
            #pragma unroll
            for (int k = 0; k < 8; ++k) acc8(acc, f[k], m[k]);
        }
    }

    uint4 o;
    o.x = (unsigned)f2bf(acc[0]) | ((unsigned)f2bf(acc[1]) << 16);
    o.y = (unsigned)f2bf(acc[2]) | ((unsigned)f2bf(acc[3]) << 16);
    o.z = (unsigned)f2bf(acc[4]) | ((unsigned)f2bf(acc[5]) << 16);
    o.w = (unsigned)f2bf(acc[6]) | ((unsigned)f2bf(acc[7]) << 16);
    *(uint4*)(ts + (size_t)node * 16 + off) = o;
}

// ---------------- fused GIN MLP, M=128, [4][N][32] layout, half-rotation LDS ----------------
// Sub-tile [slice][128 rows][64B] (8KB); physical 16B-slot = h ^ ((row>>1)&3).
__global__ __launch_bounds__(512) void k_mlp(
    const unsigned short* __restrict__ tin,
    const unsigned short* __restrict__ w1t, const float* __restrict__ b1,
    const unsigned short* __restrict__ w2t, const float* __restrict__ b2,
    unsigned short* __restrict__ hout) {
    __shared__ __align__(16) char tlds[4 * 8192];
    __shared__ __align__(16) char hlds[4 * 8192];
    const int tid = threadIdx.x, lane = tid & 63, w = tid >> 6;
    const int l15 = lane & 15, lg = lane >> 4;
    const int nbase = blockIdx.x * 128;
    const int rx = (l15 >> 1) & 3;     // ((row>>1)&3) for row = m*16 + l15

    // stage: 32 chunks of 1KB (16 nodes x 64B of one slice), source-half rotated
    #pragma unroll
    for (int i = 0; i < 4; ++i) {
        int c = w + i * 8;                 // chunk id [0,32)
        int s = c >> 3, rblk = c & 7;
        int node = nbase + rblk * 16 + (lane >> 2);
        if (node >= N_NODES) node = 0;
        int hsrc = (lane & 3) ^ ((lane >> 3) & 3);
        gld16(tin + ((size_t)s * N_NODES + node) * 32 + hsrc * 8,
              tlds + c * 1024);
    }

    // preload B1 AND B2 (wave w owns ot = w); B2 latency hides behind GEMM1
    bf16x8 B1[4], B2[4];
    const int col = w * 16 + l15;
    const float bias1 = b1[col], bias2 = b2[col];
    #pragma unroll
    for (int ks = 0; ks < 4; ++ks) {
        B1[ks] = *(const bf16x8*)(w1t + ((size_t)(w * 4 + ks) * 64 + lane) * 8);
        B2[ks] = *(const bf16x8*)(w2t + ((size_t)(w * 4 + ks) * 64 + lane) * 8);
    }
    __syncthreads();   // vmcnt(0) drains staging

    // GEMM1 -> relu -> hlds
    {
        const int hoff = ((lg ^ rx) << 4);
        bf16x8 A[2][4];
        #pragma unroll
        for (int ks = 0; ks < 4; ++ks)
            A[0][ks] = *(const bf16x8*)(tlds + ks * 8192 + l15 * 64 + hoff);
        #pragma unroll
        for (int m = 0; m < 8; ++m) {
            int cur = m & 1, nxt = cur ^ 1;
            if (m < 7) {
                int row = (m + 1) * 16 + l15;
                #pragma unroll
                for (int ks = 0; ks < 4; ++ks)
                    A[nxt][ks] = *(const bf16x8*)(tlds + ks * 8192 + row * 64 + hoff);
            }
            f32x4 acc = {0.f, 0.f, 0.f, 0.f};
            #pragma unroll
            for (int ks = 0; ks < 4; ++ks)
                acc = __builtin_amdgcn_mfma_f32_16x16x32_bf16(A[cur][ks], B1[ks], acc, 0, 0, 0);
            #pragma unroll
            for (int r = 0; r < 4; ++r) {
                int row = m * 16 + lg * 4 + r;
                int rw = (2 * lg + (r >> 1)) & 3;
                int h = (w & 1) * 2 + (l15 >> 3);
                float v = acc[r] + bias1; v = v > 0.f ? v : 0.f;
                *(unsigned short*)(hlds + (w >> 1) * 8192 + row * 64 +
                                   ((h ^ rw) << 4) + (l15 & 7) * 2) = f2bf(v);
            }
        }
    }
    __syncthreads();

    // GEMM2 -> relu -> global ([4][N][32] layout)
    {
        const int hoff = ((lg ^ rx) << 4);
        bf16x8 A[2][4];
        #pragma unroll
        for (int ks = 0; ks < 4; ++ks)
            A[0][ks] = *(const bf16x8*)(hlds + ks * 8192 + l15 * 64 + hoff);
        #pragma unroll
        for (int m = 0; m < 8; ++m) {
            int cur = m & 1, nxt = cur ^ 1;
            if (m < 7) {
                int row = (m + 1) * 16 + l15;
                #pragma unroll
                for (int ks = 0; ks < 4; ++ks)
                    A[nxt][ks] = *(const bf16x8*)(hlds + ks * 8192 + row * 64 + hoff);
            }
            f32x4 acc = {0.f, 0.f, 0.f, 0.f};
            #pragma unroll
            for (int ks = 0; ks < 4; ++ks)
                acc = __builtin_amdgcn_mfma_f32_16x16x32_bf16(A[cur][ks], B2[ks], acc, 0, 0, 0);
            #pragma unroll
            for (int r = 0; r < 4; ++r) {
                int node = nbase + m * 16 + lg * 4 + r;
                if (node < N_NODES) {
                    float v = acc[r] + bias2; v = v > 0.f ? v : 0.f;
                    hout[((size_t)(w >> 1) * N_NODES + node) * 32 + (w & 1) * 16 + l15] = f2bf(v);
                }
            }
        }
    }
}

// ---------------- fused head, M=64, [4][N][32] layout, 48KB LDS -> 2 blocks/CU ----------------
// 12 sub-tiles [64][64B] (4KB). ks in [0,12): part = ks>>2, slice = ks&3.
__global__ __launch_bounds__(512, 4) void k_final(
    const unsigned short* __restrict__ h1, const unsigned short* __restrict__ h2,
    const unsigned short* __restrict__ h3,
    const unsigned short* __restrict__ l1t, const float* __restrict__ l1b,
    const unsigned short* __restrict__ l2t, const float* __restrict__ l2b,
    float* __restrict__ out) {
    __shared__ __align__(16) char lds[12 * 4096];   // 48KB
    const int tid = threadIdx.x, lane = tid & 63, w = tid >> 6;
    const int l15 = lane & 15, lg = lane >> 4;
    const int nbase = blockIdx.x * 64;
    const int rx = (l15 >> 1) & 3;

    // stage: 48 chunks of 1KB; chunk c: sub-tile g=c>>2 (part=g>>2, slice=g&3), rows [(c&3)*16,+16)
    #pragma unroll
    for (int i = 0; i < 6; ++i) {
        int c = w + i * 8;                  // chunk id [0,48)
        int g = c >> 2, rblk = c & 3;
        int part = g >> 2, slice = g & 3;
        int node = nbase + rblk * 16 + (lane >> 2);
        if (node >= N_NODES) node = 0;
        int hsrc = (lane & 3) ^ ((lane >> 3) & 3);
        const unsigned short* hp = part == 0 ? h1 : (part == 1 ? h2 : h3);
        gld16(hp + ((size_t)slice * N_NODES + node) * 32 + hsrc * 8,
              lds + c * 1024);
    }

    // preload lin1 B for ks=0
    bf16x8 B[2][3];
    #pragma unroll
    for (int ot = 0; ot < 3; ++ot)
        B[0][ot] = *(const bf16x8*)(l1t + ((size_t)((w * 3 + ot) * 12) * 64 + lane) * 8);
    __syncthreads();   // vmcnt(0) drains staging

    // lin1: wave w owns out cols [48w, 48w+48), 4 m-tiles; B double-buffered
    f32x4 acc[4][3];
    #pragma unroll
    for (int m = 0; m < 4; ++m)
        #pragma unroll
        for (int ot = 0; ot < 3; ++ot) acc[m][ot] = {0.f, 0.f, 0.f, 0.f};
    {
        const int hoff = ((lg ^ rx) << 4);
        #pragma unroll
        for (int ks = 0; ks < 12; ++ks) {
            int cur = ks & 1, nxt = cur ^ 1;
            if (ks < 11) {
                #pragma unroll
                for (int ot = 0; ot < 3; ++ot)
                    B[nxt][ot] = *(const bf16x8*)(l1t + ((size_t)((w * 3 + ot) * 12 + ks + 1) * 64 + lane) * 8);
            }
            bf16x8 A[4];
            #pragma unroll
            for (int m = 0; m < 4; ++m) {
                int row = m * 16 + l15;
                A[m] = *(const bf16x8*)(lds + ks * 4096 + row * 64 + hoff);
            }
            #pragma unroll
            for (int ot = 0; ot < 3; ++ot)
                #pragma unroll
                for (int m = 0; m < 4; ++m)
                    acc[m][ot] = __builtin_amdgcn_mfma_f32_16x16x32_bf16(A[m], B[cur][ot], acc[m][ot], 0, 0, 0);
        }
    }
    __syncthreads();   // everyone done reading A-tile

    // relu + write hidden (bf16) into same LDS; hidden col c -> group c>>5, half (c>>3)&3
    #pragma unroll
    for (int ot = 0; ot < 3; ++ot) {
        int c = (w * 3 + ot) * 16 + l15;
        int gc = c >> 5, h = (c >> 3) & 3, b2i = (c & 7) * 2;
        float bias = l1b[c];
        #pragma unroll
        for (int m = 0; m < 4; ++m)
            #pragma unroll
            for (int r = 0; r < 4; ++r) {
                int row = m * 16 + lg * 4 + r;
                int rw = (2 * lg + (r >> 1)) & 3;
                float v = acc[m][ot][r] + bias; v = v > 0.f ? v : 0.f;
                *(unsigned short*)(lds + gc * 4096 + row * 64 + ((h ^ rw) << 4) + b2i) = f2bf(v);
            }
    }
    __syncthreads();

    // lin2 + softmax: waves 0-3 own rows [16w,+16) of the 64
    if (w < 4) {
        f32x4 acc2[3];
        #pragma unroll
        for (int ot = 0; ot < 3; ++ot) acc2[ot] = {0.f, 0.f, 0.f, 0.f};
        {
            const int row = w * 16 + l15;
            const int hoff = ((lg ^ rx) << 4);
            bf16x8 C2[2][3];
            #pragma unroll
            for (int ot = 0; ot < 3; ++ot)
                C2[0][ot] = *(const bf16x8*)(l2t + ((size_t)(ot * 12) * 64 + lane) * 8);
            #pragma unroll
            for (int ks = 0; ks < 12; ++ks) {
                int cur = ks & 1, nxt = cur ^ 1;
                if (ks < 11) {
                    #pragma unroll
                    for (int ot = 0; ot < 3; ++ot)
                        C2[nxt][ot] = *(const bf16x8*)(l2t + ((size_t)(ot * 12 + ks + 1) * 64 + lane) * 8);
                }
                bf16x8 A2 = *(const bf16x8*)(lds + ks * 4096 + row * 64 + hoff);
                #pragma unroll
                for (int ot = 0; ot < 3; ++ot)
                    acc2[ot] = __builtin_amdgcn_mfma_f32_16x16x32_bf16(A2, C2[cur][ot], acc2[ot], 0, 0, 0);
            }
        }

        int c0 = l15;
        #pragma unroll
        for (int r = 0; r < 4; ++r) {
            float v0 = acc2[0][r] + l2b[c0];
            float v1 = acc2[1][r] + l2b[c0 + 16];
            float v2 = (c0 < 8) ? (acc2[2][r] + l2b[c0 + 32]) : -1e30f;
            float mx = fmaxf(fmaxf(v0, v1), v2);
            for (int msk = 1; msk < 16; msk <<= 1) mx = fmaxf(mx, __shfl_xor(mx, msk));
            float s = __expf(v0 - mx) + __expf(v1 - mx) + ((c0 < 8) ? __expf(v2 - mx) : 0.f);
            for (int msk = 1; msk < 16; msk <<= 1) s += __shfl_xor(s, msk);
            float lse = mx + __logf(s);
            int node = nbase + w * 16 + lg * 4 + r;
            if (node < N_NODES) {
                out[(size_t)node * 40 + c0] = v0 - lse;
                out[(size_t)node * 40 + c0 + 16] = v1 - lse;
                if (c0 < 8) out[(size_t)node * 40 + c0 + 32] = v2 - lse;
            }
        }
    }
}

extern "C" void kernel_launch(void* const* d_in, const int* in_sizes, int n_in,
                              void* d_out, int out_size, void* d_ws, size_t ws_size,
                              hipStream_t stream) {
    const float* x  = (const float*)d_in[0];
    const int*   ei = (const int*)d_in[1];
    const float* gw1[3] = {(const float*)d_in[2],  (const float*)d_in[6],  (const float*)d_in[10]};
    const float* gb1[3] = {(const float*)d_in[3],  (const float*)d_in[7],  (const float*)d_in[11]};
    const float* gw2[3] = {(const float*)d_in[4],  (const float*)d_in[8],  (const float*)d_in[12]};
    const float* gb2[3] = {(const float*)d_in[5],  (const float*)d_in[9],  (const float*)d_in[13]};
    const float* l1w = (const float*)d_in[14];
    const float* l1b = (const float*)d_in[15];
    const float* l2w = (const float*)d_in[16];
    const float* l2b = (const float*)d_in[17];
    float* out = (float*)d_out;

    char* p = (char*)d_ws;
    auto alloc = [&](size_t bytes) { char* q = p; p += (bytes + 255) & ~(size_t)255; return q; };
    int* rp   = (int*)alloc(4 * (N_NODES + 1));
    int* cnt  = (int*)alloc(4 * N_NODES);
    int* cur  = (int*)alloc(4 * N_NODES);
    int* bsum = (int*)alloc(4 * 256);
    int* colv = (int*)alloc(4 * (size_t)NEDGE);
    unsigned short* t  = (unsigned short*)alloc(2 * (size_t)N_NODES * 128);
    unsigned short* h1 = (unsigned short*)alloc(2 * (size_t)N_NODES * 128);
    unsigned short* h2 = (unsigned short*)alloc(2 * (size_t)N_NODES * 128);
    unsigned short* h3 = (unsigned short*)alloc(2 * (size_t)N_NODES * 128);
    unsigned short* xs = h3;   // alias: xs dead after layer-1 agg, h3 written in layer 3
    unsigned short* wt[6];
    for (int i = 0; i < 6; ++i) wt[i] = (unsigned short*)alloc(2 * 128 * 128);
    unsigned short* l1t = (unsigned short*)alloc(2 * 384 * 384);
    unsigned short* l2t = (unsigned short*)alloc(2 * 48 * 384);

    const int nb = (N_NODES + 1023) / 1024;     // 98
    // CSR build
    hipMemsetAsync(cnt, 0, 4 * N_NODES, stream);
    k_countr<<<((NEDGE + 255) / 256) * FILL_SLICES, 256, 0, stream>>>(ei, cnt);
    k_scan1<<<nb, 256, 0, stream>>>(cnt, rp, bsum);
    k_scan2<<<1, 256, 0, stream>>>(bsum, nb);
    k_scan3<<<nb, 256, 0, stream>>>(rp, bsum, cur);
    k_fillr<<<((NEDGE + 255) / 256) * FILL_SLICES, 256, 0, stream>>>(ei, cur, colv);

    // weight prep (one dispatch, fragment-major bf16)
    k_wprep_all<<<(WPREP_TOT + 255) / 256, 256, 0, stream>>>(
        gw1[0], gw2[0], gw1[1], gw2[1], gw1[2], gw2[2], l1w, l2w, wt[0]);

    // x -> sliced bf16 [4][N][32]
    k_xprep<<<4 * ((N_NODES * 16 + 255) / 256), 256, 0, stream>>>(x, xs);

    const int gagg = ((N_NODES + AGG_NODES - 1) / AGG_NODES) * 4;
    const int gtile2 = (N_NODES + 127) / 128;
    const int gtile1 = (N_NODES + 63) / 64;
    // layer 1
    k_aggs<<<gagg, 512, 0, stream>>>(xs, t, rp, colv);
    k_mlp<<<gtile2, 512, 0, stream>>>(t, wt[0], gb1[0], wt[1], gb2[0], h1);
    // layer 2
    k_aggs<<<gagg, 512, 0, stream>>>(h1, t, rp, colv);
    k_mlp<<<gtile2, 512, 0, stream>>>(t, wt[2], gb1[1], wt[3], gb2[1], h2);
    // layer 3
    k_aggs<<<gagg, 512, 0, stream>>>(h2, t, rp, colv);
    k_mlp<<<gtile2, 512, 0, stream>>>(t, wt[4], gb1[2], wt[5], gb2[2], h3);
    // head
    k_final<<<gtile1, 512, 0, stream>>>(h1, h2, h3, l1t, l1b, l2t, l2b, out);
}